// Round 1
// baseline (179.148 us; speedup 1.0000x reference)
//
#include <hip/hip_runtime.h>

#define NNODES 100000
#define NEDGES 3200000
#define CH     128
#define KPOOL  50000
#define NBUCK  (1 << 20)          // value buckets for f64 ranking
#define BUCK_SCALE 65536.0        // NBUCK / 16 (range [-8, 8))

// output offsets (floats)
#define OFF_X   0
#define OFF_EI  6400000
#define OFF_EA  12800000
#define OFF_REG 16000000
#define OFF_BAT 16050000
#define OFF_SC  16100000
#define OFF_NE  16200000

#define NB_EDGE 782               // ceil(NEDGES / 4096)

__device__ __forceinline__ int bucketOf(double s) {
    // monotonic: score descending -> bucket ascending
    double u = (8.0 - s) * BUCK_SCALE;
    int b = (int)u;
    if (b < 0) b = 0;
    if (b > NBUCK - 1) b = NBUCK - 1;
    return b;
}

// K1: scores (f64 accumulate), write f32 scores output, bucket histogram
__global__ void k_scores(const float* __restrict__ x, const float* __restrict__ W,
                         const float* __restrict__ bias, double* __restrict__ score_d,
                         float* __restrict__ out, unsigned* __restrict__ hist) {
    int row  = blockIdx.x * 4 + (threadIdx.x >> 6);
    int lane = threadIdx.x & 63;
    if (row >= NNODES) return;
    int c = lane * 2;
    float2 xv = *(const float2*)(x + (size_t)row * CH + c);
    double acc = (double)xv.x * (double)W[c] + (double)xv.y * (double)W[c + 1];
    for (int off = 32; off > 0; off >>= 1) acc += __shfl_down(acc, off, 64);
    if (lane == 0) {
        double s = acc + (double)bias[0];
        score_d[row] = s;
        out[OFF_SC + row] = (float)s;
        atomicAdd(&hist[bucketOf(s)], 1u);
    }
}

// S1: block-scan 1024 buckets/block of the histogram -> local-exclusive bases + block totals
__global__ void k_scan1(const unsigned* __restrict__ hist, unsigned* __restrict__ bbase,
                        unsigned* __restrict__ spart) {
    int t = threadIdx.x, blk = blockIdx.x;
    int i0 = blk * 1024 + t * 4;
    uint4 h = *(const uint4*)(hist + i0);
    unsigned s = h.x + h.y + h.z + h.w;
    __shared__ unsigned sc[256];
    sc[t] = s; __syncthreads();
    for (int off = 1; off < 256; off <<= 1) {
        unsigned v = (t >= off) ? sc[t - off] : 0u;
        __syncthreads(); sc[t] += v; __syncthreads();
    }
    unsigned excl = sc[t] - s;
    if (t == 255) spart[blk] = sc[255];
    uint4 o; o.x = excl; o.y = o.x + h.x; o.z = o.y + h.y; o.w = o.z + h.z;
    *(uint4*)(bbase + i0) = o;
}

// S2: exclusive scan of the 1024 block totals (in place)
__global__ void k_scan2(unsigned* __restrict__ spart) {
    int t = threadIdx.x;
    __shared__ unsigned sc[1024];
    unsigned v0 = spart[t];
    sc[t] = v0; __syncthreads();
    for (int off = 1; off < 1024; off <<= 1) {
        unsigned v = (t >= off) ? sc[t - off] : 0u;
        __syncthreads(); sc[t] += v; __syncthreads();
    }
    spart[t] = sc[t] - v0;
}

// S3: add block offsets
__global__ void k_scan3(unsigned* __restrict__ bbase, const unsigned* __restrict__ spart) {
    int t = threadIdx.x, blk = blockIdx.x;
    int i0 = blk * 1024 + t * 4;
    unsigned add = spart[blk];
    uint4 v = *(uint4*)(bbase + i0);
    v.x += add; v.y += add; v.z += add; v.w += add;
    *(uint4*)(bbase + i0) = v;
}

// C: scatter node ids into bucket slots
__global__ void k_scatter(const double* __restrict__ score_d, const unsigned* __restrict__ bbase,
                          unsigned* __restrict__ bcnt, unsigned* __restrict__ elems) {
    int i = blockIdx.x * 256 + threadIdx.x;
    if (i >= NNODES) return;
    int b = bucketOf(score_d[i]);
    unsigned slot = bbase[b] + atomicAdd(&bcnt[b], 1u);
    elems[slot] = i;
}

// R: exact rank (descending score, tie -> lower index) via same-bucket compares
__global__ void k_rank(const double* __restrict__ score_d, const unsigned* __restrict__ bbase,
                       const unsigned* __restrict__ hist, const unsigned* __restrict__ elems,
                       unsigned* __restrict__ perm, unsigned char* __restrict__ keep) {
    int i = blockIdx.x * 256 + threadIdx.x;
    if (i >= NNODES) return;
    double s = score_d[i];
    int b = bucketOf(s);
    unsigned st = bbase[b], c = hist[b];
    unsigned r = st;
    if (c > 1) {
        for (unsigned m = 0; m < c; ++m) {
            unsigned j = elems[st + m];
            if (j == (unsigned)i) continue;
            double sj = score_d[j];
            if (sj > s || (sj == s && j < (unsigned)i)) r++;
        }
    }
    perm[r] = (unsigned)i;
    keep[i] = (r < KPOOL) ? 1 : 0;
}

// P: gather pooled x rows + region/batch
__global__ void k_pool(const float* __restrict__ x, const int* __restrict__ region,
                       const int* __restrict__ batch, const unsigned* __restrict__ perm,
                       float* __restrict__ out) {
    int r    = blockIdx.x * 4 + (threadIdx.x >> 6);
    int lane = threadIdx.x & 63;
    if (r >= KPOOL) return;
    unsigned i = perm[r];
    float2 v = *(const float2*)(x + (size_t)i * CH + lane * 2);
    *(float2*)(out + OFF_X + (size_t)r * CH + lane * 2) = v;
    if (lane == 0) {
        out[OFF_REG + r] = (float)region[i];
        out[OFF_BAT + r] = (float)batch[i];
    }
}

// E0: fill edge outputs (edge_index = -1, edge_attr = 0); head overwritten later
__global__ void k_fill(float* __restrict__ out) {
    int idx = blockIdx.x * 256 + threadIdx.x;   // float4 index over 2.4M
    float4 v;
    float f = (idx < 1600000) ? -1.0f : 0.0f;
    v.x = f; v.y = f; v.z = f; v.w = f;
    *(float4*)(out + OFF_EI + (size_t)idx * 4) = v;
}

// E1: edge keep-mask + per-block counts (4096 edges/block, 16/thread contiguous)
__global__ void k_emask(const int* __restrict__ ei, const unsigned char* __restrict__ keep,
                        unsigned char* __restrict__ emask, unsigned* __restrict__ epart) {
    int t = threadIdx.x, blk = blockIdx.x;
    long e0 = (long)blk * 4096 + (long)t * 16;
    unsigned cnt = 0;
    for (int q = 0; q < 16; ++q) {
        long e = e0 + q;
        if (e < NEDGES) {
            int a = ei[e], b = ei[NEDGES + e];
            unsigned char m = keep[a] & keep[b];
            emask[e] = m;
            cnt += m;
        }
    }
    __shared__ unsigned sc[256];
    sc[t] = cnt; __syncthreads();
    for (int off = 128; off > 0; off >>= 1) {
        if (t < off) sc[t] += sc[t + off];
        __syncthreads();
    }
    if (t == 0) epart[blk] = sc[0];
}

// E2: exclusive scan of NB_EDGE block counts; write total as num_edges_kept
__global__ void k_escan(const unsigned* __restrict__ epart, unsigned* __restrict__ epartx,
                        float* __restrict__ out) {
    int t = threadIdx.x;
    __shared__ unsigned sc[1024];
    unsigned v0 = (t < NB_EDGE) ? epart[t] : 0u;
    sc[t] = v0; __syncthreads();
    for (int off = 1; off < 1024; off <<= 1) {
        unsigned v = (t >= off) ? sc[t - off] : 0u;
        __syncthreads(); sc[t] += v; __syncthreads();
    }
    if (t < NB_EDGE) epartx[t] = sc[t] - v0;
    if (t == 0) out[OFF_NE] = (float)sc[1023];
}

// E3: stable scatter of kept edges
__global__ void k_escatter(const int* __restrict__ ei, const float* __restrict__ attr,
                           const unsigned char* __restrict__ emask,
                           const unsigned* __restrict__ epartx, float* __restrict__ out) {
    int t = threadIdx.x, blk = blockIdx.x;
    long e0 = (long)blk * 4096 + (long)t * 16;
    unsigned cnt = 0;
    for (int q = 0; q < 16; ++q) {
        long e = e0 + q;
        if (e < NEDGES) cnt += emask[e];
    }
    __shared__ unsigned sc[256];
    sc[t] = cnt; __syncthreads();
    for (int off = 1; off < 256; off <<= 1) {
        unsigned v = (t >= off) ? sc[t - off] : 0u;
        __syncthreads(); sc[t] += v; __syncthreads();
    }
    unsigned pos = epartx[blk] + sc[t] - cnt;
    for (int q = 0; q < 16; ++q) {
        long e = e0 + q;
        if (e < NEDGES && emask[e]) {
            out[OFF_EI + pos]          = (float)ei[e];
            out[OFF_EI + NEDGES + pos] = (float)ei[NEDGES + e];
            out[OFF_EA + pos]          = attr[e];
            pos++;
        }
    }
}

extern "C" void kernel_launch(void* const* d_in, const int* in_sizes, int n_in,
                              void* d_out, int out_size, void* d_ws, size_t ws_size,
                              hipStream_t stream) {
    const float* x      = (const float*)d_in[0];
    const int*   ei     = (const int*)d_in[1];
    const float* attr   = (const float*)d_in[2];
    const int*   region = (const int*)d_in[3];
    const int*   batch  = (const int*)d_in[4];
    const float* W      = (const float*)d_in[5];
    const float* bias   = (const float*)d_in[6];
    float* out = (float*)d_out;

    char* ws = (char*)d_ws;
    double*        score_d = (double*)(ws + 0);              //   800,000 B
    unsigned*      hist    = (unsigned*)(ws + 800000);       // 4,194,304 B
    unsigned*      bbase   = (unsigned*)(ws + 4994304);      // 4,194,304 B
    unsigned*      bcnt    = (unsigned*)(ws + 9188608);      // 4,194,304 B
    unsigned*      elems   = (unsigned*)(ws + 13382912);     //   400,000 B
    unsigned*      perm    = (unsigned*)(ws + 13782912);     //   400,000 B
    unsigned char* keep    = (unsigned char*)(ws + 14182912);//   100,000 B
    unsigned*      spart   = (unsigned*)(ws + 14282912);     //     4,096 B
    unsigned char* emask   = (unsigned char*)(ws + 14287008);// 3,200,000 B
    unsigned*      epart   = (unsigned*)(ws + 17487008);     //     4,096 B
    unsigned*      epartx  = (unsigned*)(ws + 17491104);     //     4,096 B

    hipMemsetAsync(hist, 0, (size_t)NBUCK * 4, stream);
    hipMemsetAsync(bcnt, 0, (size_t)NBUCK * 4, stream);

    k_scores<<<NNODES / 4, 256, 0, stream>>>(x, W, bias, score_d, out, hist);
    k_scan1<<<NBUCK / 1024, 256, 0, stream>>>(hist, bbase, spart);
    k_scan2<<<1, 1024, 0, stream>>>(spart);
    k_scan3<<<NBUCK / 1024, 256, 0, stream>>>(bbase, spart);
    k_scatter<<<(NNODES + 255) / 256, 256, 0, stream>>>(score_d, bbase, bcnt, elems);
    k_rank<<<(NNODES + 255) / 256, 256, 0, stream>>>(score_d, bbase, hist, elems, perm, keep);
    k_pool<<<KPOOL / 4, 256, 0, stream>>>(x, region, batch, perm, out);
    k_fill<<<9375, 256, 0, stream>>>(out);
    k_emask<<<NB_EDGE, 256, 0, stream>>>(ei, keep, emask, epart);
    k_escan<<<1, 1024, 0, stream>>>(epart, epartx, out);
    k_escatter<<<NB_EDGE, 256, 0, stream>>>(ei, attr, emask, epartx, out);
}

// Round 3
// 99.419 us; speedup vs baseline: 1.8019x; 1.8019x over previous
//
#include <hip/hip_runtime.h>

#define NNODES 100000
#define NEDGES 3200000
#define CH     128
#define KPOOL  50000
#define NBUCK  (1 << 17)          // value buckets for f64 ranking
#define BUCK_SCALE 8192.0         // NBUCK / 16 (range [-8, 8))

// output offsets (floats)
#define OFF_X   0
#define OFF_EI  6400000
#define OFF_EA  12800000
#define OFF_REG 16000000
#define OFF_BAT 16050000
#define OFF_SC  16100000
#define OFF_NE  16200000

#define NB_EDGE 3125              // NEDGES / 1024

__device__ __forceinline__ int bucketOf(double s) {
    // monotonic: score descending -> bucket ascending
    double u = (8.0 - s) * BUCK_SCALE;
    int b = (int)u;
    if (b < 0) b = 0;
    if (b > NBUCK - 1) b = NBUCK - 1;
    return b;
}

// K1: scores (f64 accumulate -- DO NOT change reduction order), f32 scores out, histogram
__global__ void k_scores(const float* __restrict__ x, const float* __restrict__ W,
                         const float* __restrict__ bias, double* __restrict__ score_d,
                         float* __restrict__ out, unsigned* __restrict__ hist) {
    int row  = blockIdx.x * 4 + (threadIdx.x >> 6);
    int lane = threadIdx.x & 63;
    if (row >= NNODES) return;
    int c = lane * 2;
    float2 xv = *(const float2*)(x + (size_t)row * CH + c);
    double acc = (double)xv.x * (double)W[c] + (double)xv.y * (double)W[c + 1];
    for (int off = 32; off > 0; off >>= 1) acc += __shfl_down(acc, off, 64);
    if (lane == 0) {
        double s = acc + (double)bias[0];
        score_d[row] = s;
        out[OFF_SC + row] = (float)s;
        atomicAdd(&hist[bucketOf(s)], 1u);
    }
}

// S1: block-scan 1024 buckets/block -> local-exclusive bases + block totals
__global__ void k_scan1(const unsigned* __restrict__ hist, unsigned* __restrict__ bbase,
                        unsigned* __restrict__ spart) {
    int t = threadIdx.x, blk = blockIdx.x;
    int i0 = blk * 1024 + t * 4;
    uint4 h = *(const uint4*)(hist + i0);
    unsigned s = h.x + h.y + h.z + h.w;
    __shared__ unsigned sc[256];
    sc[t] = s; __syncthreads();
    for (int off = 1; off < 256; off <<= 1) {
        unsigned v = (t >= off) ? sc[t - off] : 0u;
        __syncthreads(); sc[t] += v; __syncthreads();
    }
    unsigned excl = sc[t] - s;
    if (t == 255) spart[blk] = sc[255];
    uint4 o; o.x = excl; o.y = o.x + h.x; o.z = o.y + h.y; o.w = o.z + h.z;
    *(uint4*)(bbase + i0) = o;
}

// S2: exclusive scan of the 128 block totals (in place)
__global__ void k_scan2(unsigned* __restrict__ spart) {
    int t = threadIdx.x;
    __shared__ unsigned sc[128];
    unsigned v0 = spart[t];
    sc[t] = v0; __syncthreads();
    for (int off = 1; off < 128; off <<= 1) {
        unsigned v = (t >= off) ? sc[t - off] : 0u;
        __syncthreads(); sc[t] += v; __syncthreads();
    }
    spart[t] = sc[t] - v0;
}

// C: scatter node ids into bucket slots (bbase + spart fused at use-site)
__global__ void k_scatter(const double* __restrict__ score_d, const unsigned* __restrict__ bbase,
                          const unsigned* __restrict__ spart, unsigned* __restrict__ bcnt,
                          unsigned* __restrict__ elems) {
    int i = blockIdx.x * 256 + threadIdx.x;
    if (i >= NNODES) return;
    int b = bucketOf(score_d[i]);
    unsigned base = bbase[b] + spart[b >> 10];
    unsigned slot = base + atomicAdd(&bcnt[b], 1u);
    elems[slot] = i;
}

// R: exact rank (desc score, tie -> lower index); set keep bit for r < KPOOL
__global__ void k_rank(const double* __restrict__ score_d, const unsigned* __restrict__ bbase,
                       const unsigned* __restrict__ spart, const unsigned* __restrict__ hist,
                       const unsigned* __restrict__ elems, unsigned* __restrict__ perm,
                       unsigned* __restrict__ kb) {
    int i = blockIdx.x * 256 + threadIdx.x;
    if (i >= NNODES) return;
    double s = score_d[i];
    int b = bucketOf(s);
    unsigned st = bbase[b] + spart[b >> 10], c = hist[b];
    unsigned r = st;
    if (c > 1) {
        for (unsigned m = 0; m < c; ++m) {
            unsigned j = elems[st + m];
            if (j == (unsigned)i) continue;
            double sj = score_d[j];
            if (sj > s || (sj == s && j < (unsigned)i)) r++;
        }
    }
    perm[r] = (unsigned)i;
    if (r < KPOOL) atomicOr(&kb[i >> 5], 1u << (i & 31));
}

// P: gather pooled x rows + region/batch (wave per row, coalesced)
__global__ void k_pool(const float* __restrict__ x, const int* __restrict__ region,
                       const int* __restrict__ batch, const unsigned* __restrict__ perm,
                       float* __restrict__ out) {
    int r    = blockIdx.x * 4 + (threadIdx.x >> 6);
    int lane = threadIdx.x & 63;
    if (r >= KPOOL) return;
    unsigned i = perm[r];
    float2 v = *(const float2*)(x + (size_t)i * CH + lane * 2);
    *(float2*)(out + OFF_X + (size_t)r * CH + lane * 2) = v;
    if (lane == 0) {
        out[OFF_REG + r] = (float)region[i];
        out[OFF_BAT + r] = (float)batch[i];
    }
}

// E1: per-block kept-edge counts (1024 edges/block, int4 loads, bit-mask from L1 table)
__global__ void k_ecount(const int* __restrict__ ei, const unsigned* __restrict__ kb,
                         unsigned* __restrict__ epart) {
    int t = threadIdx.x, blk = blockIdx.x;
    size_t e0 = (size_t)blk * 1024 + (size_t)t * 4;
    int4 a = *(const int4*)(ei + e0);
    int4 b = *(const int4*)(ei + NEDGES + e0);
    unsigned c = 0;
    c += (kb[a.x >> 5] >> (a.x & 31)) & (kb[b.x >> 5] >> (b.x & 31)) & 1u;
    c += (kb[a.y >> 5] >> (a.y & 31)) & (kb[b.y >> 5] >> (b.y & 31)) & 1u;
    c += (kb[a.z >> 5] >> (a.z & 31)) & (kb[b.z >> 5] >> (b.z & 31)) & 1u;
    c += (kb[a.w >> 5] >> (a.w & 31)) & (kb[b.w >> 5] >> (b.w & 31)) & 1u;
    __shared__ unsigned sc[256];
    sc[t] = c; __syncthreads();
    for (int off = 128; off > 0; off >>= 1) {
        if (t < off) sc[t] += sc[t + off];
        __syncthreads();
    }
    if (t == 0) epart[blk] = sc[0];
}

// E2: exclusive scan of 3125 block counts; publish total
__global__ void k_escan(const unsigned* __restrict__ epart, unsigned* __restrict__ epartx,
                        int* __restrict__ ntotal, float* __restrict__ out) {
    int t = threadIdx.x;
    unsigned v[4]; unsigned s = 0;
    for (int q = 0; q < 4; ++q) { int i = t * 4 + q; v[q] = (i < NB_EDGE) ? epart[i] : 0u; s += v[q]; }
    __shared__ unsigned sc[1024];
    sc[t] = s; __syncthreads();
    for (int off = 1; off < 1024; off <<= 1) {
        unsigned w = (t >= off) ? sc[t - off] : 0u;
        __syncthreads(); sc[t] += w; __syncthreads();
    }
    unsigned excl = sc[t] - s;
    for (int q = 0; q < 4; ++q) { int i = t * 4 + q; if (i < NB_EDGE) epartx[i] = excl; excl += v[q]; }
    if (t == 1023) { *ntotal = (int)sc[1023]; out[OFF_NE] = (float)sc[1023]; }
}

// E3: stable compaction via LDS staging + coalesced write-out; tail fill fused
__global__ void k_escatter(const int* __restrict__ ei, const float* __restrict__ attr,
                           const unsigned* __restrict__ kb, const unsigned* __restrict__ epartx,
                           const int* __restrict__ ntotal, float* __restrict__ out) {
    int t = threadIdx.x, blk = blockIdx.x;
    size_t e0 = (size_t)blk * 1024 + (size_t)t * 4;
    int4 a = *(const int4*)(ei + e0);
    int4 b = *(const int4*)(ei + NEDGES + e0);
    float4 at = *(const float4*)(attr + e0);
    unsigned m0 = (kb[a.x >> 5] >> (a.x & 31)) & (kb[b.x >> 5] >> (b.x & 31)) & 1u;
    unsigned m1 = (kb[a.y >> 5] >> (a.y & 31)) & (kb[b.y >> 5] >> (b.y & 31)) & 1u;
    unsigned m2 = (kb[a.z >> 5] >> (a.z & 31)) & (kb[b.z >> 5] >> (b.z & 31)) & 1u;
    unsigned m3 = (kb[a.w >> 5] >> (a.w & 31)) & (kb[b.w >> 5] >> (b.w & 31)) & 1u;
    unsigned cnt = m0 + m1 + m2 + m3;
    __shared__ unsigned sc[256];
    __shared__ float sA[1024], sB[1024], sT[1024];
    sc[t] = cnt; __syncthreads();
    for (int off = 1; off < 256; off <<= 1) {
        unsigned w = (t >= off) ? sc[t - off] : 0u;
        __syncthreads(); sc[t] += w; __syncthreads();
    }
    unsigned p = sc[t] - cnt;
    if (m0) { sA[p] = (float)a.x; sB[p] = (float)b.x; sT[p] = at.x; p++; }
    if (m1) { sA[p] = (float)a.y; sB[p] = (float)b.y; sT[p] = at.y; p++; }
    if (m2) { sA[p] = (float)a.z; sB[p] = (float)b.z; sT[p] = at.z; p++; }
    if (m3) { sA[p] = (float)a.w; sB[p] = (float)b.w; sT[p] = at.w; p++; }
    __syncthreads();
    unsigned cntAll = sc[255];
    unsigned base = epartx[blk];
    for (unsigned u = t; u < cntAll; u += 256) {
        out[OFF_EI + base + u]          = sA[u];
        out[OFF_EI + NEDGES + base + u] = sB[u];
        out[OFF_EA + base + u]          = sT[u];
    }
    // fused tail fill: [total, NEDGES) gets -1 / -1 / 0, sliced across blocks
    int total = *ntotal;
    size_t tlen = (size_t)NEDGES - (size_t)total;
    size_t chunk = (tlen + NB_EDGE - 1) / NB_EDGE;
    size_t s0 = (size_t)total + (size_t)blk * chunk;
    size_t s1 = s0 + chunk; if (s1 > (size_t)NEDGES) s1 = (size_t)NEDGES;
    for (size_t q = s0 + (size_t)t; q < s1; q += 256) {
        out[OFF_EI + q]          = -1.0f;
        out[OFF_EI + NEDGES + q] = -1.0f;
        out[OFF_EA + q]          = 0.0f;
    }
}

extern "C" void kernel_launch(void* const* d_in, const int* in_sizes, int n_in,
                              void* d_out, int out_size, void* d_ws, size_t ws_size,
                              hipStream_t stream) {
    const float* x      = (const float*)d_in[0];
    const int*   ei     = (const int*)d_in[1];
    const float* attr   = (const float*)d_in[2];
    const int*   region = (const int*)d_in[3];
    const int*   batch  = (const int*)d_in[4];
    const float* W      = (const float*)d_in[5];
    const float* bias   = (const float*)d_in[6];
    float* out = (float*)d_out;

    char* ws = (char*)d_ws;
    double*   score_d = (double*)(ws + 0);            // 800,000 B
    unsigned* hist    = (unsigned*)(ws + 800000);     // 524,288 B (memset region start)
    unsigned* bcnt    = (unsigned*)(ws + 1324288);    // 524,288 B (memset)
    unsigned* kb      = (unsigned*)(ws + 1848576);    // 12,544 B  (memset region end)
    unsigned* bbase   = (unsigned*)(ws + 1861120);    // 524,288 B
    unsigned* elems   = (unsigned*)(ws + 2385408);    // 400,000 B
    unsigned* perm    = (unsigned*)(ws + 2785408);    // 400,000 B
    unsigned* spart   = (unsigned*)(ws + 3185408);    // 512 B
    unsigned* epart   = (unsigned*)(ws + 3185920);    // 12,512 B
    unsigned* epartx  = (unsigned*)(ws + 3198432);    // 12,512 B
    int*      ntotal  = (int*)(ws + 3210944);         // 4 B

    (void)hipMemsetAsync(ws + 800000, 0, 1061120, stream);  // hist + bcnt + kb

    k_scores  <<<NNODES / 4, 256, 0, stream>>>(x, W, bias, score_d, out, hist);
    k_scan1   <<<NBUCK / 1024, 256, 0, stream>>>(hist, bbase, spart);
    k_scan2   <<<1, 128, 0, stream>>>(spart);
    k_scatter <<<(NNODES + 255) / 256, 256, 0, stream>>>(score_d, bbase, spart, bcnt, elems);
    k_rank    <<<(NNODES + 255) / 256, 256, 0, stream>>>(score_d, bbase, spart, hist, elems, perm, kb);
    k_pool    <<<KPOOL / 4, 256, 0, stream>>>(x, region, batch, perm, out);
    k_ecount  <<<NB_EDGE, 256, 0, stream>>>(ei, kb, epart);
    k_escan   <<<1, 1024, 0, stream>>>(epart, epartx, ntotal, out);
    k_escatter<<<NB_EDGE, 256, 0, stream>>>(ei, attr, kb, epartx, ntotal, out);
}